// Round 1
// baseline (150.952 us; speedup 1.0000x reference)
//
#include <hip/hip_runtime.h>

#define HW    256
#define HW2   (HW*HW)
#define KTAPS 25
#define TW    32          // tile width  (outputs)
#define TH    8           // tile height (outputs)
#define LW    36          // LDS row length (TW + 4); 36*4=144 B, 16B-aligned rows
#define LH    12          // TH + 4
#define NEL   (LW*LH)     // 432
#define NSTG  7           // ceil(432/64); stage covers 448 slots (overrun is benign, buffer sized for it)
#define BUFSZ (NSTG*64)   // 448 floats per ring buffer
#define NRING 4           // ring depth 4: reads of a buffer are 2 iterations older than its overwrite
#define CPB   8           // channels per block (channel-split = 4)
#define C     32

// Issue the 7 async global->LDS loads for one channel tile.
// Global source address is per-lane (clamped edge-replicate already folded into soff);
// LDS dest is wave-uniform base + lane*4 (hardware layout), matching idx = k*64 + lane.
__device__ __forceinline__ void stage(const float* __restrict__ src, float* dst,
                                      const int* __restrict__ soff) {
#pragma unroll
    for (int k = 0; k < NSTG; ++k)
        __builtin_amdgcn_global_load_lds(
            (const __attribute__((address_space(1))) unsigned int*)(src + soff[k]),
            (__attribute__((address_space(3))) unsigned int*)(dst + k * 64),
            4, 0, 0);
}

__global__ __launch_bounds__(64, 4) void ddown_kernel(
    const float* __restrict__ x,
    const float* __restrict__ kern,
    float* __restrict__ out)
{
    __shared__ __align__(16) float xt[NRING][BUFSZ];   // 4 * 1792 B = 7168 B

    const int lane = threadIdx.x;      // one wave per block: no __syncthreads anywhere
    const int txq  = lane & 7;         // 8 thread-columns of 4 outputs
    const int ty   = lane >> 3;        // 8 rows
    const int w0   = blockIdx.x * TW;
    const int h0   = blockIdx.y * TH;
    const int b    = blockIdx.z >> 2;
    const int c0   = (blockIdx.z & 3) * CPB;

    const int h = h0 + ty;
    const int w = w0 + txq * 4;

    const float* xb = x + (size_t)(b * C + c0) * HW2;

    // Per-lane clamped source offsets for the 7 stage slots, hoisted out of the
    // channel loop (saves ~70 VALU ops x 8 channels per thread vs recomputing).
    // k=6 lanes 48..63 map to idx 432..447 -> i=12, j=0..15: still clamped-valid,
    // lands in the buffer's 432..447 pad slots. No masking needed.
    int soff[NSTG];
#pragma unroll
    for (int k = 0; k < NSTG; ++k) {
        int idx = lane + k * 64;
        int i   = idx / LW;
        int j   = idx - i * LW;
        int hh  = min(max(h0 + i - 2, 0), HW - 1);
        int ww  = min(max(w0 + j - 2, 0), HW - 1);
        soff[k] = hh * HW + ww;
    }

    // Prologue: channels 0 and 1 in flight before the softmax phase even starts.
    stage(xb,       xt[0], soff);
    stage(xb + HW2, xt[1], soff);

    // ---- softmax weights for this thread's 4 pixels (unnormalized; fold 1/S later) ----
    const float* kb = kern + (size_t)b * KTAPS * HW2 + h * HW + w;
    float4 wt[KTAPS];
    float sx = 0.f, sy = 0.f, sz = 0.f, sw = 0.f;
#pragma unroll
    for (int j = 0; j < KTAPS; ++j) {
        float4 v = *(const float4*)(kb + (size_t)j * HW2);
        v.x = __expf(v.x); v.y = __expf(v.y); v.z = __expf(v.z); v.w = __expf(v.w);
        sx += v.x; sy += v.y; sz += v.z; sw += v.w;
        wt[j] = v;
    }
    const float ix = 1.f / sx, iy = 1.f / sy, iz = 1.f / sz, iw = 1.f / sw;

    float* ob = out + (size_t)(b * C + c0) * HW2 + h * HW + w;

#pragma unroll
    for (int cc = 0; cc < CPB; ++cc) {
        // Keep the pipeline 2 deep: issue channel cc+2 BEFORE waiting on cc.
        if (cc + 2 < CPB) stage(xb + (size_t)(cc + 2) * HW2, xt[(cc + 2) % NRING], soff);

        // Counted waits (never vmcnt(0) in steady state). FIFO accounting, loads only
        // (safe whether or not stores tick vmcnt): newer-than-S_cc = S_{cc+1}+S_{cc+2} = 14.
        // Tail: cc==6 -> only S7 newer (7); cc==7 -> drain.
        if (cc < 6)       asm volatile("s_waitcnt vmcnt(14)" ::: "memory");
        else if (cc == 6) asm volatile("s_waitcnt vmcnt(7)"  ::: "memory");
        else              asm volatile("s_waitcnt vmcnt(0)"  ::: "memory");

        const float* xc = xt[cc % NRING];
        float ax = 0.f, ay = 0.f, az = 0.f, aw = 0.f;
#pragma unroll
        for (int di = 0; di < 5; ++di) {
            const float* row = &xc[(ty + di) * LW + txq * 4];
            float4 pa = *(const float4*)(row);      // ds_read_b128
            float4 pb = *(const float4*)(row + 4);  // ds_read_b128
            float w8[8] = {pa.x, pa.y, pa.z, pa.w, pb.x, pb.y, pb.z, pb.w};
#pragma unroll
            for (int dj = 0; dj < 5; ++dj) {
                float4 wv = wt[di * 5 + dj];
                ax += wv.x * w8[dj + 0];
                ay += wv.y * w8[dj + 1];
                az += wv.z * w8[dj + 2];
                aw += wv.w * w8[dj + 3];
            }
        }
        float4 res = { ax * ix, ay * iy, az * iz, aw * iw };
        *(float4*)(ob + (size_t)cc * HW2) = res;
    }
}

extern "C" void kernel_launch(void* const* d_in, const int* in_sizes, int n_in,
                              void* d_out, int out_size, void* d_ws, size_t ws_size,
                              hipStream_t stream) {
    const float* x    = (const float*)d_in[0];
    const float* kern = (const float*)d_in[1];
    float* out        = (float*)d_out;

    dim3 grid(HW / TW, HW / TH, 4 * 4);   // (8, 32, 16) = 4096 single-wave blocks
    ddown_kernel<<<grid, 64, 0, stream>>>(x, kern, out);
}

// Round 2
// 115.347 us; speedup vs baseline: 1.3087x; 1.3087x over previous
//
#include <hip/hip_runtime.h>

#define HW    256
#define HW2   (HW*HW)
#define KTAPS 25
#define TW    32          // tile width  (outputs)
#define TH    8           // tile height (outputs)
#define LW    36          // LDS row length (TW + 4); 36*4=144 B, 16B-aligned rows
#define LH    12          // TH + 4
#define NEL   (LW*LH)     // 432
#define NSTG  7           // ceil(432/64); stage covers 448 slots (overrun is benign, buffer sized for it)
#define BUFSZ (NSTG*64)   // 448 floats per ring buffer
#define NRING 4           // ring depth 4: reads of a buffer are 2 iterations older than its overwrite
#define CPB   8           // channels per block (channel-split = 4)
#define C     32

// Issue the 7 async global->LDS loads for one channel tile.
// Global source address is per-lane (clamped edge-replicate already folded into soff);
// LDS dest is wave-uniform base + lane*4 (hardware layout), matching idx = k*64 + lane.
__device__ __forceinline__ void stage(const float* __restrict__ src, float* dst,
                                      const int* __restrict__ soff) {
#pragma unroll
    for (int k = 0; k < NSTG; ++k)
        __builtin_amdgcn_global_load_lds(
            (const __attribute__((address_space(1))) unsigned int*)(src + soff[k]),
            (__attribute__((address_space(3))) unsigned int*)(dst + k * 64),
            4, 0, 0);
}

// launch_bounds(64,3): unified VGPR+AGPR cap ~170. This kernel needs ~140 live
// (100 weight floats + 7 soff + addressing); (64,4)'s 128-cap spilled wt[] to
// scratch (+130 MB HBM traffic, round-1 post-mortem). Do not raise to 4.
__global__ __launch_bounds__(64, 3) void ddown_kernel(
    const float* __restrict__ x,
    const float* __restrict__ kern,
    float* __restrict__ out)
{
    __shared__ __align__(16) float xt[NRING][BUFSZ];   // 4 * 1792 B = 7168 B

    const int lane = threadIdx.x;      // one wave per block: no __syncthreads anywhere
    const int txq  = lane & 7;         // 8 thread-columns of 4 outputs
    const int ty   = lane >> 3;        // 8 rows
    const int w0   = blockIdx.x * TW;
    const int h0   = blockIdx.y * TH;
    const int b    = blockIdx.z >> 2;
    const int c0   = (blockIdx.z & 3) * CPB;

    const int h = h0 + ty;
    const int w = w0 + txq * 4;

    const float* xb = x + (size_t)(b * C + c0) * HW2;

    // Per-lane clamped source offsets for the 7 stage slots, hoisted out of the
    // channel loop (saves ~70 VALU ops x 8 channels per thread vs recomputing).
    // k=6 lanes 48..63 map to idx 432..447 -> i=12, j=0..15: still clamped-valid,
    // lands in the buffer's 432..447 pad slots. No masking needed.
    int soff[NSTG];
#pragma unroll
    for (int k = 0; k < NSTG; ++k) {
        int idx = lane + k * 64;
        int i   = idx / LW;
        int j   = idx - i * LW;
        int hh  = min(max(h0 + i - 2, 0), HW - 1);
        int ww  = min(max(w0 + j - 2, 0), HW - 1);
        soff[k] = hh * HW + ww;
    }

    // Prologue: channels 0 and 1 in flight before the softmax phase even starts.
    stage(xb,       xt[0], soff);
    stage(xb + HW2, xt[1], soff);

    // ---- softmax weights for this thread's 4 pixels (unnormalized; fold 1/S later) ----
    const float* kb = kern + (size_t)b * KTAPS * HW2 + h * HW + w;
    float4 wt[KTAPS];
    float sx = 0.f, sy = 0.f, sz = 0.f, sw = 0.f;
#pragma unroll
    for (int j = 0; j < KTAPS; ++j) {
        float4 v = *(const float4*)(kb + (size_t)j * HW2);
        v.x = __expf(v.x); v.y = __expf(v.y); v.z = __expf(v.z); v.w = __expf(v.w);
        sx += v.x; sy += v.y; sz += v.z; sw += v.w;
        wt[j] = v;
    }
    const float ix = 1.f / sx, iy = 1.f / sy, iz = 1.f / sz, iw = 1.f / sw;

    float* ob = out + (size_t)(b * C + c0) * HW2 + h * HW + w;

#pragma unroll
    for (int cc = 0; cc < CPB; ++cc) {
        // Keep the pipeline 2 deep: issue channel cc+2 BEFORE waiting on cc.
        if (cc + 2 < CPB) stage(xb + (size_t)(cc + 2) * HW2, xt[(cc + 2) % NRING], soff);

        // Counted waits (never vmcnt(0) in steady state). FIFO accounting, loads only
        // (safe whether or not stores tick vmcnt): newer-than-S_cc = S_{cc+1}+S_{cc+2} = 14.
        // Tail: cc==6 -> only S7 newer (7); cc==7 -> drain.
        if (cc < 6)       asm volatile("s_waitcnt vmcnt(14)" ::: "memory");
        else if (cc == 6) asm volatile("s_waitcnt vmcnt(7)"  ::: "memory");
        else              asm volatile("s_waitcnt vmcnt(0)"  ::: "memory");

        const float* xc = xt[cc % NRING];
        float ax = 0.f, ay = 0.f, az = 0.f, aw = 0.f;
#pragma unroll
        for (int di = 0; di < 5; ++di) {
            const float* row = &xc[(ty + di) * LW + txq * 4];
            float4 pa = *(const float4*)(row);      // ds_read_b128
            float4 pb = *(const float4*)(row + 4);  // ds_read_b128
            float w8[8] = {pa.x, pa.y, pa.z, pa.w, pb.x, pb.y, pb.z, pb.w};
#pragma unroll
            for (int dj = 0; dj < 5; ++dj) {
                float4 wv = wt[di * 5 + dj];
                ax += wv.x * w8[dj + 0];
                ay += wv.y * w8[dj + 1];
                az += wv.z * w8[dj + 2];
                aw += wv.w * w8[dj + 3];
            }
        }
        float4 res = { ax * ix, ay * iy, az * iz, aw * iw };
        *(float4*)(ob + (size_t)cc * HW2) = res;
    }
}

extern "C" void kernel_launch(void* const* d_in, const int* in_sizes, int n_in,
                              void* d_out, int out_size, void* d_ws, size_t ws_size,
                              hipStream_t stream) {
    const float* x    = (const float*)d_in[0];
    const float* kern = (const float*)d_in[1];
    float* out        = (float*)d_out;

    dim3 grid(HW / TW, HW / TH, 4 * 4);   // (8, 32, 16) = 4096 single-wave blocks
    ddown_kernel<<<grid, 64, 0, stream>>>(x, kern, out);
}